// Round 1
// baseline (51.310 us; speedup 1.0000x reference)
//
#include <hip/hip_runtime.h>
#include <math.h>

#define RBLOCKS 1024
#define RTHREADS 256

// ---------------------------------------------------------------------------
// Stage 1: per-block partial sums of q^2 (double accumulation, deterministic)
// ---------------------------------------------------------------------------
__global__ __launch_bounds__(RTHREADS) void gp_reduce_sq(
    const float4* __restrict__ q4, int n4, double* __restrict__ partials) {
    __shared__ double sdata[RTHREADS];
    double acc = 0.0;
    int stride = gridDim.x * blockDim.x;
    for (int i = blockIdx.x * blockDim.x + threadIdx.x; i < n4; i += stride) {
        float4 v = q4[i];
        acc += (double)v.x * v.x + (double)v.y * v.y +
               (double)v.z * v.z + (double)v.w * v.w;
    }
    sdata[threadIdx.x] = acc;
    __syncthreads();
    for (int s = RTHREADS / 2; s > 0; s >>= 1) {
        if (threadIdx.x < s) sdata[threadIdx.x] += sdata[threadIdx.x + s];
        __syncthreads();
    }
    if (threadIdx.x == 0) partials[blockIdx.x] = sdata[0];
}

// ---------------------------------------------------------------------------
// Stage 2: reduce partials -> inv_norm = 1/sqrt(sum) (single block)
// ---------------------------------------------------------------------------
__global__ __launch_bounds__(RTHREADS) void gp_finalize_norm(
    const double* __restrict__ partials, float* __restrict__ inv_norm) {
    __shared__ double sdata[RTHREADS];
    double acc = 0.0;
    for (int i = threadIdx.x; i < RBLOCKS; i += RTHREADS) acc += partials[i];
    sdata[threadIdx.x] = acc;
    __syncthreads();
    for (int s = RTHREADS / 2; s > 0; s >>= 1) {
        if (threadIdx.x < s) sdata[threadIdx.x] += sdata[threadIdx.x + s];
        __syncthreads();
    }
    if (threadIdx.x == 0) *inv_norm = (float)(1.0 / sqrt(sdata[0]));
}

// ---------------------------------------------------------------------------
// Stage 3: pointwise cov / inv_cov / sigmoid
// cov = R diag(exp(2s)) R^T ; inv_cov = R diag(exp(-2s)) R^T
// ---------------------------------------------------------------------------
__global__ __launch_bounds__(256) void gp_main(
    const float4* __restrict__ q,
    const float* __restrict__ scales,
    const float* __restrict__ opac_in,
    const float* __restrict__ inv_norm_p,
    float* __restrict__ cov,
    float* __restrict__ inv_cov,
    float* __restrict__ opac_out,
    int n) {
    const float inv_norm = *inv_norm_p;
    int stride = gridDim.x * blockDim.x;
    for (int i = blockIdx.x * blockDim.x + threadIdx.x; i < n; i += stride) {
        float4 qi = q[i];
        float w = qi.x * inv_norm;
        float x = qi.y * inv_norm;
        float y = qi.z * inv_norm;
        float z = qi.w * inv_norm;

        float xx = x * x, yy = y * y, zz = z * z;
        float xy = x * y, xz = x * z, yz = y * z;
        float xw = x * w, yw = y * w, zw = z * w;

        float r00 = 1.f - 2.f * (yy + zz);
        float r01 = 2.f * (xy - zw);
        float r02 = 2.f * (xz + yw);
        float r10 = 2.f * (xy + zw);
        float r11 = 1.f - 2.f * (xx + zz);
        float r12 = 2.f * (yz - xw);
        float r20 = 2.f * (xz - yw);
        float r21 = 2.f * (yz + xw);
        float r22 = 1.f - 2.f * (xx + yy);

        float s0 = scales[3 * (size_t)i];
        float s1 = scales[3 * (size_t)i + 1];
        float s2 = scales[3 * (size_t)i + 2];

        float e0 = expf(2.f * s0), e1 = expf(2.f * s1), e2 = expf(2.f * s2);
        float f0 = expf(-2.f * s0), f1 = expf(-2.f * s1), f2 = expf(-2.f * s2);

        size_t base = (size_t)i * 9;

        // cov = R * diag(e) * R^T
        {
            float a0 = r00 * e0, a1 = r01 * e1, a2 = r02 * e2;
            float b0 = r10 * e0, b1 = r11 * e1, b2 = r12 * e2;
            float c0 = r20 * e0, c1 = r21 * e1, c2 = r22 * e2;
            float m00 = a0 * r00 + a1 * r01 + a2 * r02;
            float m01 = a0 * r10 + a1 * r11 + a2 * r12;
            float m02 = a0 * r20 + a1 * r21 + a2 * r22;
            float m11 = b0 * r10 + b1 * r11 + b2 * r12;
            float m12 = b0 * r20 + b1 * r21 + b2 * r22;
            float m22 = c0 * r20 + c1 * r21 + c2 * r22;
            cov[base + 0] = m00;
            cov[base + 1] = m01;
            cov[base + 2] = m02;
            cov[base + 3] = m01;
            cov[base + 4] = m11;
            cov[base + 5] = m12;
            cov[base + 6] = m02;
            cov[base + 7] = m12;
            cov[base + 8] = m22;
        }
        // inv_cov = R * diag(f) * R^T
        {
            float a0 = r00 * f0, a1 = r01 * f1, a2 = r02 * f2;
            float b0 = r10 * f0, b1 = r11 * f1, b2 = r12 * f2;
            float c0 = r20 * f0, c1 = r21 * f1, c2 = r22 * f2;
            float m00 = a0 * r00 + a1 * r01 + a2 * r02;
            float m01 = a0 * r10 + a1 * r11 + a2 * r12;
            float m02 = a0 * r20 + a1 * r21 + a2 * r22;
            float m11 = b0 * r10 + b1 * r11 + b2 * r12;
            float m12 = b0 * r20 + b1 * r21 + b2 * r22;
            float m22 = c0 * r20 + c1 * r21 + c2 * r22;
            inv_cov[base + 0] = m00;
            inv_cov[base + 1] = m01;
            inv_cov[base + 2] = m02;
            inv_cov[base + 3] = m01;
            inv_cov[base + 4] = m11;
            inv_cov[base + 5] = m12;
            inv_cov[base + 6] = m02;
            inv_cov[base + 7] = m12;
            inv_cov[base + 8] = m22;
        }
        // opacity: sigmoid
        {
            float o = opac_in[i];
            opac_out[i] = 1.f / (1.f + expf(-o));
        }
    }
}

extern "C" void kernel_launch(void* const* d_in, const int* in_sizes, int n_in,
                              void* d_out, int out_size, void* d_ws, size_t ws_size,
                              hipStream_t stream) {
    const float* q = (const float*)d_in[0];        // (N,4)
    const float* scales = (const float*)d_in[1];   // (N,3)
    const float* opac = (const float*)d_in[2];     // (N,1)
    int n = in_sizes[0] / 4;
    int n4 = in_sizes[0] / 4;  // number of float4 in quaternions == n

    float* out = (float*)d_out;
    float* cov = out;                       // N*9
    float* inv_cov = out + (size_t)n * 9;   // N*9
    float* opac_out = out + (size_t)n * 18; // N

    // ws layout: [0 .. RBLOCKS) doubles = partials ; then 1 float inv_norm
    double* partials = (double*)d_ws;
    float* inv_norm = (float*)((char*)d_ws + RBLOCKS * sizeof(double));

    gp_reduce_sq<<<RBLOCKS, RTHREADS, 0, stream>>>(
        (const float4*)q, n4, partials);
    gp_finalize_norm<<<1, RTHREADS, 0, stream>>>(partials, inv_norm);

    int blocks = 2048;
    gp_main<<<blocks, 256, 0, stream>>>(
        (const float4*)q, scales, opac, inv_norm,
        cov, inv_cov, opac_out, n);
}

// Round 2
// 44.721 us; speedup vs baseline: 1.1473x; 1.1473x over previous
//
#include <hip/hip_runtime.h>
#include <math.h>

#define RBLOCKS 1024
#define RTHREADS 256
#define CHUNK 256

// ---------------------------------------------------------------------------
// Stage 1: per-block partial sums of q^2 (double accumulation, deterministic)
// ---------------------------------------------------------------------------
__global__ __launch_bounds__(RTHREADS) void gp_reduce_sq(
    const float4* __restrict__ q4, int n4, double* __restrict__ partials) {
    __shared__ double sdata[RTHREADS];
    double acc = 0.0;
    int stride = gridDim.x * blockDim.x;
    for (int i = blockIdx.x * blockDim.x + threadIdx.x; i < n4; i += stride) {
        float4 v = q4[i];
        acc += (double)v.x * v.x + (double)v.y * v.y +
               (double)v.z * v.z + (double)v.w * v.w;
    }
    sdata[threadIdx.x] = acc;
    __syncthreads();
    for (int s = RTHREADS / 2; s > 0; s >>= 1) {
        if (threadIdx.x < s) sdata[threadIdx.x] += sdata[threadIdx.x + s];
        __syncthreads();
    }
    if (threadIdx.x == 0) partials[blockIdx.x] = sdata[0];
}

// ---------------------------------------------------------------------------
// Stage 2 (fused): every block reduces the 1024 partials itself
// (identical deterministic result per block), then computes its chunk of
// 256 gaussians and stores cov/inv_cov via LDS-staged coalesced float4.
// ---------------------------------------------------------------------------
__global__ __launch_bounds__(256) void gp_main(
    const float4* __restrict__ q,
    const float* __restrict__ scales,
    const float* __restrict__ opac_in,
    const double* __restrict__ partials,
    float* __restrict__ cov,
    float* __restrict__ inv_cov,
    float* __restrict__ opac_out,
    int n) {
    __shared__ union SU {
        double red[4];
        float mat[2 * CHUNK * 9];  // [0..2304) cov, [2304..4608) inv_cov
    } u;
    __shared__ float s_sc[CHUNK * 3];

    const int tid = threadIdx.x;
    const int c0 = blockIdx.x * CHUNK;
    const int count = min(CHUNK, n - c0);

    // ---- issue input loads early ----
    float4 qi = make_float4(0.f, 0.f, 0.f, 0.f);
    float op = 0.f;
    if (tid < count) {
        qi = q[c0 + tid];
        op = opac_in[c0 + tid];
    }
    // stage scales via coalesced float4 loads
    const int nsf = count * 3;            // floats of scales in this chunk
    const int nsf4 = nsf >> 2;            // float4 count (<=192)
    const float4* sc4 = (const float4*)(scales + (size_t)c0 * 3);
    float4 sv = make_float4(0.f, 0.f, 0.f, 0.f);
    if (tid < nsf4) sv = sc4[tid];

    // ---- norm: reduce 1024 partials (deterministic, same in every block) ----
    double acc = 0.0;
#pragma unroll
    for (int k = 0; k < RBLOCKS / 256; ++k) acc += partials[tid + 256 * k];
#pragma unroll
    for (int off = 32; off > 0; off >>= 1) acc += __shfl_down(acc, off);
    if ((tid & 63) == 0) u.red[tid >> 6] = acc;

    // park scales into LDS (separate region, no alias with u.red)
    if (tid < nsf4) {
        s_sc[4 * tid + 0] = sv.x;
        s_sc[4 * tid + 1] = sv.y;
        s_sc[4 * tid + 2] = sv.z;
        s_sc[4 * tid + 3] = sv.w;
    }
    {   // scalar remainder of scales (nsf not multiple of 4)
        int r = nsf - nsf4 * 4;
        if (tid < r) s_sc[nsf4 * 4 + tid] = scales[(size_t)c0 * 3 + nsf4 * 4 + tid];
    }
    __syncthreads();

    double tot = u.red[0] + u.red[1] + u.red[2] + u.red[3];
    const float inv_norm = (float)(1.0 / sqrt(tot));
    __syncthreads();  // all reads of u.red done before u.mat overwrites it

    // ---- compute ----
    if (tid < count) {
        float w = qi.x * inv_norm;
        float x = qi.y * inv_norm;
        float y = qi.z * inv_norm;
        float z = qi.w * inv_norm;

        float xx = x * x, yy = y * y, zz = z * z;
        float xy = x * y, xz = x * z, yz = y * z;
        float xw = x * w, yw = y * w, zw = z * w;

        float r00 = 1.f - 2.f * (yy + zz);
        float r01 = 2.f * (xy - zw);
        float r02 = 2.f * (xz + yw);
        float r10 = 2.f * (xy + zw);
        float r11 = 1.f - 2.f * (xx + zz);
        float r12 = 2.f * (yz - xw);
        float r20 = 2.f * (xz - yw);
        float r21 = 2.f * (yz + xw);
        float r22 = 1.f - 2.f * (xx + yy);

        float s0 = s_sc[3 * tid + 0];
        float s1 = s_sc[3 * tid + 1];
        float s2 = s_sc[3 * tid + 2];

        float e0 = expf(2.f * s0), e1 = expf(2.f * s1), e2 = expf(2.f * s2);
        float f0 = 1.f / e0, f1 = 1.f / e1, f2 = 1.f / e2;

        float* mc = &u.mat[tid * 9];
        float* mi = &u.mat[CHUNK * 9 + tid * 9];
        {
            float a0 = r00 * e0, a1 = r01 * e1, a2 = r02 * e2;
            float b0 = r10 * e0, b1 = r11 * e1, b2 = r12 * e2;
            float c0_ = r20 * e0, c1 = r21 * e1, c2 = r22 * e2;
            float m00 = a0 * r00 + a1 * r01 + a2 * r02;
            float m01 = a0 * r10 + a1 * r11 + a2 * r12;
            float m02 = a0 * r20 + a1 * r21 + a2 * r22;
            float m11 = b0 * r10 + b1 * r11 + b2 * r12;
            float m12 = b0 * r20 + b1 * r21 + b2 * r22;
            float m22 = c0_ * r20 + c1 * r21 + c2 * r22;
            mc[0] = m00; mc[1] = m01; mc[2] = m02;
            mc[3] = m01; mc[4] = m11; mc[5] = m12;
            mc[6] = m02; mc[7] = m12; mc[8] = m22;
        }
        {
            float a0 = r00 * f0, a1 = r01 * f1, a2 = r02 * f2;
            float b0 = r10 * f0, b1 = r11 * f1, b2 = r12 * f2;
            float c0_ = r20 * f0, c1 = r21 * f1, c2 = r22 * f2;
            float m00 = a0 * r00 + a1 * r01 + a2 * r02;
            float m01 = a0 * r10 + a1 * r11 + a2 * r12;
            float m02 = a0 * r20 + a1 * r21 + a2 * r22;
            float m11 = b0 * r10 + b1 * r11 + b2 * r12;
            float m12 = b0 * r20 + b1 * r21 + b2 * r22;
            float m22 = c0_ * r20 + c1 * r21 + c2 * r22;
            mi[0] = m00; mi[1] = m01; mi[2] = m02;
            mi[3] = m01; mi[4] = m11; mi[5] = m12;
            mi[6] = m02; mi[7] = m12; mi[8] = m22;
        }
        // opacity (coalesced scalar store)
        opac_out[c0 + tid] = 1.f / (1.f + expf(-op));
    }
    __syncthreads();

    // ---- coalesced float4 stores of cov / inv_cov ----
    const int nf = count * 9;
    const int nfv = nf >> 2;  // float4 count (576 full chunk)
    float4* covo = (float4*)(cov + (size_t)c0 * 9);
    float4* invo = (float4*)(inv_cov + (size_t)c0 * 9);
    const float4* mc4 = (const float4*)u.mat;
    const float4* mi4 = (const float4*)(u.mat + CHUNK * 9);
    for (int j = tid; j < nfv; j += 256) covo[j] = mc4[j];
    for (int j = tid; j < nfv; j += 256) invo[j] = mi4[j];
    // scalar remainder (nf not multiple of 4 — only possible in tail block)
    for (int j = nfv * 4 + tid; j < nf; j += 256) {
        cov[(size_t)c0 * 9 + j] = u.mat[j];
        inv_cov[(size_t)c0 * 9 + j] = u.mat[CHUNK * 9 + j];
    }
}

extern "C" void kernel_launch(void* const* d_in, const int* in_sizes, int n_in,
                              void* d_out, int out_size, void* d_ws, size_t ws_size,
                              hipStream_t stream) {
    const float* q = (const float*)d_in[0];        // (N,4)
    const float* scales = (const float*)d_in[1];   // (N,3)
    const float* opac = (const float*)d_in[2];     // (N,1)
    int n = in_sizes[0] / 4;

    float* out = (float*)d_out;
    float* cov = out;                        // N*9
    float* inv_cov = out + (size_t)n * 9;    // N*9
    float* opac_out = out + (size_t)n * 18;  // N

    double* partials = (double*)d_ws;  // RBLOCKS doubles

    gp_reduce_sq<<<RBLOCKS, RTHREADS, 0, stream>>>((const float4*)q, n, partials);

    int nblocks = (n + CHUNK - 1) / CHUNK;
    gp_main<<<nblocks, 256, 0, stream>>>(
        (const float4*)q, scales, opac, partials,
        cov, inv_cov, opac_out, n);
}